// Round 6
// baseline (466.422 us; speedup 1.0000x reference)
//
#include <hip/hip_runtime.h>
#include <math.h>

#define TT 2
#define CC 64
#define HH 160
#define WW 160
#define KS 7
#define K2 49
#define NSPIX 196
#define HWSZ (HH*WW)
#define PAD 3
#define OO 64
#define FANIN (CC*K2)
#define TS 8
#define PS (TS+KS-1)   // 14
#define NPOS (PS*PS)   // 196

#define NCHUNK 25
#define CHUNKPIX 1024
#define NBLK 800

typedef _Float16 half8 __attribute__((ext_vector_type(8)));
typedef float f32x16 __attribute__((ext_vector_type(16)));
typedef unsigned int uint4v __attribute__((ext_vector_type(4)));
typedef _Float16 half2v __attribute__((ext_vector_type(2)));

__device__ __forceinline__ int reflect(int i, int n) {
    if (i < 0) i = -i;
    if (i >= n) i = 2*n - 2 - i;
    return i;
}

// Software grid barrier. Safe because all NBLK blocks are co-resident by
// construction (LDS 33168B -> 4 blocks/CU, VGPR<=128 via launch_bounds,
// 800 <= 1024 slots) and every block participates. Agent-scope acq_rel
// atomics emit buffer_wbl2/buffer_inv on gfx950 -> cross-XCD visibility.
__device__ __forceinline__ void grid_barrier(unsigned int* cnt, unsigned int* flag) {
    __syncthreads();   // drains vmcnt -> all block stores in L2
    if (threadIdx.x == 0 && threadIdx.y == 0) {
        __threadfence();   // release: wbl2
        unsigned int a = __hip_atomic_fetch_add(cnt, 1u, __ATOMIC_ACQ_REL,
                                                __HIP_MEMORY_SCOPE_AGENT);
        if (a == NBLK - 1u) {
            __hip_atomic_store(flag, 1u, __ATOMIC_RELEASE, __HIP_MEMORY_SCOPE_AGENT);
        } else {
            while (__hip_atomic_load(flag, __ATOMIC_ACQUIRE,
                                     __HIP_MEMORY_SCOPE_AGENT) == 0u)
                __builtin_amdgcn_s_sleep(8);
        }
        __threadfence();   // acquire: inv L1/L2 stale lines
    }
    __syncthreads();
}

// ONE fused kernel (plus the memset node): 2 graph nodes instead of 4.
//  A: [0,400) seg accumulate+flush; [400,600) scale + xT emit; [600,698) Wb build
//  barrier
//  B: pwd (float4), spread over all 800 blocks
//  barrier
//  C: MFMA main — the proven 51 µs structure (direct global A loads, no
//     per-tap barrier; u16 rwb; normalization folded into f32 epilogue)
__global__ __launch_bounds__(256, 4) void k_fused(
    const float* __restrict__ x, const int* __restrict__ spix,
    const float* __restrict__ Wl, const float* __restrict__ b_lin,
    const float* __restrict__ wsc, const float* __restrict__ bsc,
    float* __restrict__ sums, float* __restrict__ cnts,
    unsigned int* __restrict__ bar,
    float* __restrict__ pwd, float* __restrict__ scale,
    _Float16* __restrict__ Wb, _Float16* __restrict__ xT,
    float* __restrict__ out)
{
    __shared__ unsigned short xpT[NPOS*64];   // 25088 B (phase C); ls alias (phase A)
    __shared__ unsigned short rwb[K2*64];     // 6272 B (phase C); lcnt alias (phase A)
    __shared__ int   sp[NPOS];                // 784 B
    __shared__ float mxp[4*64];               // 1024 B
    // total 33168 B -> 4 blocks/CU

    int bid = blockIdx.x;
    int tid = threadIdx.y*64 + threadIdx.x;

    // ================= phase A =================
    if (bid < 400) {
        float* ls   = (float*)xpT;     // 8*200 floats
        float* lcnt = (float*)rwb;     // 200 floats
        int cg_ = bid & 7;
        int rest = bid >> 3;          // 0..49
        int ch = rest % NCHUNK;       // 0..24
        int t  = rest / NCHUNK;       // 0..1

        for (int i = tid; i < 8*200; i += 256) ls[i] = 0.f;
        if (cg_ == 0) for (int i = tid; i < 200; i += 256) lcnt[i] = 0.f;
        __syncthreads();

        int base = ch*CHUNKPIX;
        const float* xb = x + ((size_t)t*CC + cg_*8)*HWSZ;
        #pragma unroll
        for (int i = 0; i < CHUNKPIX; i += 256) {
            int pix = base + i + tid;
            int s = spix[t*HWSZ + pix];
            if (cg_ == 0) atomicAdd(&lcnt[s], 1.0f);
            #pragma unroll
            for (int j = 0; j < 8; ++j) atomicAdd(&ls[j*200 + s], xb[(size_t)j*HWSZ + pix]);
        }
        __syncthreads();

        float* sb = sums + (size_t)t*NSPIX*CC + cg_*8;
        for (int i = tid; i < 8*NSPIX; i += 256) {
            int s = i >> 3, j = i & 7;
            float v = ls[j*200 + s];
            if (v != 0.f) atomicAdd(&sb[s*CC + j], v);
        }
        if (cg_ == 0)
            for (int i = tid; i < NSPIX; i += 256) {
                float v = lcnt[i];
                if (v != 0.f) atomicAdd(&cnts[t*NSPIX + i], v);
            }
    } else if (bid < 600) {
        int pix = (bid - 400)*256 + tid;
        int t = pix / HWSZ, hw = pix - t*HWSZ;
        const float* xs = x + (size_t)t*CC*HWSZ + hw;
        float s1 = 0.f, s2 = 0.f;
        unsigned int pk[32];
        #pragma unroll
        for (int cp = 0; cp < 32; ++cp) {
            float v0 = xs[(size_t)(2*cp)*HWSZ];
            float v1 = xs[(size_t)(2*cp + 1)*HWSZ];
            s1 += wsc[2*cp]*v0 + wsc[2*cp+1]*v1;
            s2 = fmaf(v0, v0, s2); s2 = fmaf(v1, v1, s2);
            half2v h; h[0] = (_Float16)v0; h[1] = (_Float16)v1;
            pk[cp] = __builtin_bit_cast(unsigned int, h);
        }
        float z = s1/(sqrtf(s2) + 1e-10f) + bsc[0];
        float sp_ = (z > 0.f) ? z + log1pf(expf(-z)) : log1pf(expf(z));
        scale[pix] = 10.f*sp_;
        uint4v* dst = (uint4v*)(xT + (size_t)pix*64);
        #pragma unroll
        for (int q = 0; q < 8; ++q) {
            uint4v v = { pk[4*q], pk[4*q+1], pk[4*q+2], pk[4*q+3] };
            dst[q] = v;
        }
    } else if (bid < 698) {
        int row = (bid - 600)*256 + tid;
        if (row < 2*K2*4*64) {
            int ln  = row & 63;
            int kc  = (row >> 6) & 3;
            int tq  = row >> 8;
            int tap = tq % K2;
            int qo  = tq / K2;
            int o = qo*32 + (ln & 31);
            int cb = kc*16 + (ln >> 5)*8;
            _Float16* dst = Wb + (size_t)row*8;
            const float* src = Wl + (size_t)o*FANIN + tap;
            #pragma unroll
            for (int j = 0; j < 8; ++j) dst[j] = (_Float16)src[(size_t)(cb + j)*K2];
        }
    }

    grid_barrier(&bar[0], &bar[1]);

    // ================= phase B: pwd =================
    {
        int idx = bid*256 + tid;
        if (idx < TT*NSPIX*NSPIX) {
            int t = idx / (NSPIX*NSPIX); int r = idx - t*NSPIX*NSPIX;
            int s = r / NSPIX, u = r - (r / NSPIX)*NSPIX;
            const float4* ds4 = (const float4*)(sums + (size_t)(t*NSPIX + s)*CC);
            const float4* du4 = (const float4*)(sums + (size_t)(t*NSPIX + u)*CC);
            float is = 1.0f / fmaxf(cnts[t*NSPIX + s], 1.0f);
            float iu = 1.0f / fmaxf(cnts[t*NSPIX + u], 1.0f);
            float acc = 0.f;
            #pragma unroll
            for (int q = 0; q < 16; ++q) {
                float4 a = ds4[q], b = du4[q];
                float d0 = a.x*is - b.x*iu;
                float d1 = a.y*is - b.y*iu;
                float d2 = a.z*is - b.z*iu;
                float d3 = a.w*is - b.w*iu;
                acc = fmaf(d0, d0, acc);
                acc = fmaf(d1, d1, acc);
                acc = fmaf(d2, d2, acc);
                acc = fmaf(d3, d3, acc);
            }
            pwd[idx] = acc;
        }
    }

    grid_barrier(&bar[2], &bar[3]);

    // ================= phase C: MFMA main =================
    int t = bid / 400;
    int r = bid - t*400;
    int th0 = (r / 20)*TS, tw0 = (r - (r/20)*20)*TS;

    for (int i = tid; i < NPOS; i += 256) {
        int rr = reflect(th0 + i/PS - PAD, HH);
        int cc = reflect(tw0 + i%PS - PAD, WW);
        sp[i] = spix[t*HWSZ + rr*WW + cc];
    }
    // stage xpT from xT: coalesced 16B loads, XOR-swizzled 16B-chunk writes
    {
        const _Float16* xt = xT + (size_t)t*HWSZ*64;
        for (int i = tid; i < NPOS*8; i += 256) {
            int pos = i >> 3, cb = i & 7;
            int rr = reflect(th0 + pos/PS - PAD, HH);
            int cc = reflect(tw0 + pos%PS - PAD, WW);
            uint4v v = *(const uint4v*)(xt + (size_t)(rr*WW + cc)*64 + cb*8);
            int chunk = cb ^ (pos & 7);
            *(uint4v*)&xpT[pos*64 + chunk*8] = v;
        }
    }
    __syncthreads();

    // rw build (raw f16; per-pixel max to mxp; normalization applied in epilogue)
    int p_ = threadIdx.x;
    int ty = threadIdx.y;
    int py0 = p_ >> 3, px0 = p_ & 7;
    {
        float sc = scale[t*HWSZ + (th0 + py0)*WW + (tw0 + px0)];
        int s0 = sp[(py0 + PAD)*PS + (px0 + PAD)];
        const float* pr = pwd + (t*NSPIX + s0)*NSPIX;
        float pmax = 0.f;
        for (int k = ty; k < K2; k += 4) {
            int di = k/KS, dj = k - di*KS;
            int nb = sp[(py0 + di)*PS + (px0 + dj)];
            float v = __expf(-sc * pr[nb]);
            rwb[k*64 + p_] = __builtin_bit_cast(unsigned short, (_Float16)v);
            pmax = fmaxf(pmax, v);
        }
        mxp[ty*64 + p_] = pmax;
    }
    __syncthreads();

    int ln = threadIdx.x;
    int wv = __builtin_amdgcn_readfirstlane(threadIdx.y);
    int qp = wv & 1, kh = wv >> 1;
    int p  = qp*32 + (ln & 31);
    int ppy = p >> 3, ppx = p & 7;
    int lhi = ln >> 5;

    int jc0 = 4*kh + lhi, jc1 = jc0 + 2;

    const _Float16* A0b = Wb + (size_t)(2*kh)*512 + ln*8;   // qo=0, kc0=2kh
    const _Float16* A1b = A0b + (size_t)K2*4*512;           // qo=1

    f32x16 acc0, acc1;
    #pragma unroll
    for (int i = 0; i < 16; ++i) { acc0[i] = 0.f; acc1[i] = 0.f; }

    int di = 0, dj = 0;
    #pragma unroll 7
    for (int tap = 0; tap < K2; ++tap) {
        const _Float16* a0 = A0b + (size_t)tap*2048;
        half8 A00 = *(const half8*)(a0);
        half8 A01 = *(const half8*)(a0 + 512);
        const _Float16* a1 = A1b + (size_t)tap*2048;
        half8 A10 = *(const half8*)(a1);
        half8 A11 = *(const half8*)(a1 + 512);

        int pos = (ppy + di)*PS + (ppx + dj);
        int sw  = pos & 7;
        const unsigned short* bbase = &xpT[pos*64];
        half8 B0 = *(const half8*)(bbase + ((jc0 ^ sw) << 3));
        half8 B1 = *(const half8*)(bbase + ((jc1 ^ sw) << 3));

        _Float16 rh = __builtin_bit_cast(_Float16, rwb[tap*64 + p]);
        half8 rv8 = { rh, rh, rh, rh, rh, rh, rh, rh };
        half8 b0 = B0 * rv8;
        half8 b1 = B1 * rv8;

        acc0 = __builtin_amdgcn_mfma_f32_32x32x16_f16(A00, b0, acc0, 0, 0, 0);
        acc1 = __builtin_amdgcn_mfma_f32_32x32x16_f16(A10, b0, acc1, 0, 0, 0);
        acc0 = __builtin_amdgcn_mfma_f32_32x32x16_f16(A01, b1, acc0, 0, 0, 0);
        acc1 = __builtin_amdgcn_mfma_f32_32x32x16_f16(A11, b1, acc1, 0, 0, 0);

        if (++dj == KS) { dj = 0; ++di; }
    }

    // cross-kh reduction (reuse xpT as f32 buffer)
    __syncthreads();
    float* red = (float*)xpT;
    if (kh == 1) {
        #pragma unroll
        for (int i = 0; i < 16; ++i) {
            red[((qp*2 + 0)*16 + i)*64 + ln] = acc0[i];
            red[((qp*2 + 1)*16 + i)*64 + ln] = acc1[i];
        }
    }
    __syncthreads();
    if (kh == 0) {
        // per-pixel normalizer, factored out of the einsum
        float m = fmaxf(fmaxf(mxp[p], mxp[64 + p]), fmaxf(mxp[128 + p], mxp[192 + p]));
        float s = 1.f/(1e-5f + m);
        int h = th0 + ppy, w = tw0 + ppx;
        int row_hi = 4*lhi;
        float* ob = out + (size_t)t*OO*HWSZ + h*WW + w;
        #pragma unroll
        for (int rg = 0; rg < 16; ++rg) {
            int o0 = (rg & 3) + 8*(rg >> 2) + row_hi;
            int o1 = 32 + o0;
            float v0 = acc0[rg] + red[((qp*2 + 0)*16 + rg)*64 + ln];
            float v1 = acc1[rg] + red[((qp*2 + 1)*16 + rg)*64 + ln];
            ob[(size_t)o0*HWSZ] = v0*s + b_lin[o0];
            ob[(size_t)o1*HWSZ] = v1*s + b_lin[o1];
        }
    }
}

extern "C" void kernel_launch(void* const* d_in, const int* in_sizes, int n_in,
                              void* d_out, int out_size, void* d_ws, size_t ws_size,
                              hipStream_t stream) {
    const float* x    = (const float*)d_in[0];
    const int*   spix = (const int*)d_in[1];
    const float* Wl   = (const float*)d_in[2];
    const float* bl   = (const float*)d_in[3];
    const float* wsc  = (const float*)d_in[4];
    const float* bsc  = (const float*)d_in[5];
    float* out = (float*)d_out;

    float* ws    = (float*)d_ws;
    float* sums  = ws;                             // 25088 f32
    float* cnts  = sums + TT*NSPIX*CC;             // 392 f32
    unsigned int* bar = (unsigned int*)(cnts + TT*NSPIX);  // 8 u32 (barrier state)
    float* pwd   = (float*)(bar + 8);              // 76832 f32
    float* scale = pwd  + TT*NSPIX*NSPIX;          // 51200 f32
    _Float16* Wb = (_Float16*)(scale + TT*HWSZ);   // 200704 f16
    _Float16* xT = Wb + (size_t)2*K2*4*64*8;       // 3276800 f16 (6.55 MB)

    // zeroes sums + cnts + barrier counters/flags in one node
    hipMemsetAsync(sums, 0, (size_t)(TT*NSPIX*CC + TT*NSPIX + 8)*sizeof(float), stream);

    k_fused<<<NBLK, dim3(64, 4, 1), 0, stream>>>(x, spix, Wl, bl, wsc, bsc,
                                                 sums, cnts, bar, pwd, scale,
                                                 Wb, xT, out);
}

// Round 7
// 168.121 us; speedup vs baseline: 2.7743x; 2.7743x over previous
//
#include <hip/hip_runtime.h>
#include <math.h>

#define TT 2
#define CC 64
#define HH 160
#define WW 160
#define KS 7
#define K2 49
#define NSPIX 196
#define HWSZ (HH*WW)
#define PAD 3
#define OO 64
#define FANIN (CC*K2)
#define TS 8
#define PS (TS+KS-1)   // 14
#define NPOS (PS*PS)   // 196

#define NCHUNK 25
#define CHUNKPIX 1024

typedef _Float16 half8 __attribute__((ext_vector_type(8)));
typedef float f32x16 __attribute__((ext_vector_type(16)));
typedef unsigned int uint4v __attribute__((ext_vector_type(4)));
typedef _Float16 half2v __attribute__((ext_vector_type(2)));

__device__ __forceinline__ int reflect(int i, int n) {
    if (i < 0) i = -i;
    if (i >= n) i = 2*n - 2 - i;
    return i;
}

// fused prep: [0,400) seg (LDS accumulate + atomic flush to sums/cnts);
//             [400,600) scale + xT (f16 transposed) emit; [600,698) Wb (f16) build
__global__ __launch_bounds__(256) void k_prep(const float* __restrict__ x,
                                              const int* __restrict__ spix,
                                              const float* __restrict__ Wl,
                                              const float* __restrict__ wsc,
                                              const float* __restrict__ bsc,
                                              float* __restrict__ sums,
                                              float* __restrict__ cnts,
                                              float* __restrict__ scale,
                                              _Float16* __restrict__ Wb,
                                              _Float16* __restrict__ xT) {
    __shared__ float ls[8*200];
    __shared__ float lcnt[200];
    int bid = blockIdx.x;
    int tid = threadIdx.x;

    if (bid < 400) {
        int cg = bid & 7;
        int rest = bid >> 3;          // 0..49
        int ch = rest % NCHUNK;       // 0..24
        int t  = rest / NCHUNK;       // 0..1

        for (int i = tid; i < 8*200; i += 256) ls[i] = 0.f;
        if (cg == 0) for (int i = tid; i < 200; i += 256) lcnt[i] = 0.f;
        __syncthreads();

        int base = ch*CHUNKPIX;
        const float* xb = x + ((size_t)t*CC + cg*8)*HWSZ;
        #pragma unroll
        for (int i = 0; i < CHUNKPIX; i += 256) {
            int pix = base + i + tid;
            int s = spix[t*HWSZ + pix];
            if (cg == 0) atomicAdd(&lcnt[s], 1.0f);
            #pragma unroll
            for (int j = 0; j < 8; ++j) atomicAdd(&ls[j*200 + s], xb[(size_t)j*HWSZ + pix]);
        }
        __syncthreads();

        float* sb = sums + (size_t)t*NSPIX*CC + cg*8;
        for (int i = tid; i < 8*NSPIX; i += 256) {
            int s = i >> 3, j = i & 7;
            float v = ls[j*200 + s];
            if (v != 0.f) atomicAdd(&sb[s*CC + j], v);
        }
        if (cg == 0)
            for (int i = tid; i < NSPIX; i += 256) {
                float v = lcnt[i];
                if (v != 0.f) atomicAdd(&cnts[t*NSPIX + i], v);
            }
    } else if (bid < 600) {
        int pix = (bid - 400)*256 + tid;
        int t = pix / HWSZ, hw = pix - t*HWSZ;
        const float* xs = x + (size_t)t*CC*HWSZ + hw;
        float s1 = 0.f, s2 = 0.f;
        unsigned int pk[32];
        #pragma unroll
        for (int cp = 0; cp < 32; ++cp) {
            float v0 = xs[(size_t)(2*cp)*HWSZ];
            float v1 = xs[(size_t)(2*cp + 1)*HWSZ];
            s1 += wsc[2*cp]*v0 + wsc[2*cp+1]*v1;
            s2 = fmaf(v0, v0, s2); s2 = fmaf(v1, v1, s2);
            half2v h; h[0] = (_Float16)v0; h[1] = (_Float16)v1;
            pk[cp] = __builtin_bit_cast(unsigned int, h);
        }
        float z = s1/(sqrtf(s2) + 1e-10f) + bsc[0];
        float sp_ = (z > 0.f) ? z + log1pf(expf(-z)) : log1pf(expf(z));
        scale[pix] = 10.f*sp_;
        uint4v* dst = (uint4v*)(xT + (size_t)pix*64);
        #pragma unroll
        for (int q = 0; q < 8; ++q) {
            uint4v v = { pk[4*q], pk[4*q+1], pk[4*q+2], pk[4*q+3] };
            dst[q] = v;
        }
    } else {
        int row = (bid - 600)*256 + tid;
        if (row < 2*K2*4*64) {
            int ln  = row & 63;
            int kc  = (row >> 6) & 3;
            int tq  = row >> 8;
            int tap = tq % K2;
            int qo  = tq / K2;
            int o = qo*32 + (ln & 31);
            int cb = kc*16 + (ln >> 5)*8;
            _Float16* dst = Wb + (size_t)row*8;
            const float* src = Wl + (size_t)o*FANIN + tap;
            #pragma unroll
            for (int j = 0; j < 8; ++j) dst[j] = (_Float16)src[(size_t)(cb + j)*K2];
        }
    }
}

// pwd directly from sums/cnts: pwd[t,s,u] = sum_c (down_s[c]-down_u[c])^2
__global__ __launch_bounds__(256) void k_pwd(const float* __restrict__ sums,
                                             const float* __restrict__ cnts,
                                             float* __restrict__ pwd) {
    int tid = blockIdx.x*256 + threadIdx.x;
    if (tid >= TT*NSPIX*NSPIX) return;
    int t = tid / (NSPIX*NSPIX); int r = tid - t*NSPIX*NSPIX;
    int s = r / NSPIX, u = r - (r / NSPIX)*NSPIX;
    const float* ds = sums + (size_t)(t*NSPIX + s)*CC;
    const float* du = sums + (size_t)(t*NSPIX + u)*CC;
    float is = 1.0f / fmaxf(cnts[t*NSPIX + s], 1.0f);
    float iu = 1.0f / fmaxf(cnts[t*NSPIX + u], 1.0f);
    float acc = 0.f;
    #pragma unroll 8
    for (int c = 0; c < CC; ++c) {
        float d = ds[c]*is - du[c]*iu;
        acc = fmaf(d, d, acc);
    }
    pwd[tid] = acc;
}

// stage one tap's full A-panel (both qo, all kc): 8 KB via global_load_lds w=16.
// Wb's per-tap layout is linear in (kc,lane) order -> wave-uniform LDS dest +
// lane*16 matches the per-lane global src exactly. (Verified correct in R4.)
__device__ __forceinline__ void stageA(const _Float16* __restrict__ Wb,
                                       _Float16* dstbuf, int tap, int w, int ln) {
    const _Float16* g0 = Wb + (size_t)tap*2048 + (w*64 + ln)*8;   // qo=0
    const _Float16* g1 = g0 + (size_t)K2*2048;                    // qo=1
    _Float16* l0 = dstbuf + w*512;
    _Float16* l1 = dstbuf + 2048 + w*512;
    __builtin_amdgcn_global_load_lds((const __attribute__((address_space(1))) unsigned int*)g0,
                                     (__attribute__((address_space(3))) unsigned int*)l0, 16, 0, 0);
    __builtin_amdgcn_global_load_lds((const __attribute__((address_space(1))) unsigned int*)g1,
                                     (__attribute__((address_space(3))) unsigned int*)l1, 16, 0, 0);
}

// MFMA main. Block = 8x8 pixel tile, 4 waves = (qp = wv&1, kh = wv>>1).
// A (Wb) staged per-tap into double-buffered LDS, pipelined 2 taps deep with
// COUNTED vmcnt (never 0 in steady state) + raw s_barrier — T3/T4 discipline.
// Halves A L2 traffic (qp-pair shares one copy) without R4's per-tap drain.
__global__ __launch_bounds__(256, 3) void k_main(
    const _Float16* __restrict__ xT, const int* __restrict__ spix,
    const _Float16* __restrict__ Wb, const float* __restrict__ b_lin,
    const float* __restrict__ pwd, const float* __restrict__ scale,
    float* __restrict__ out)
{
    __shared__ unsigned short xpT[NPOS*64];   // 25088 B, XOR-swizzled f16
    __shared__ unsigned short rwb[K2*64];     // 6272 B (f16)
    __shared__ _Float16 Ast[2][4096];         // 16384 B, double-buffered A panel
    __shared__ int   sp[NPOS];                // 784 B
    __shared__ float mxp[4*64];               // 1024 B
    // total 49552 B -> 3 blocks/CU

    // XCD-aware swizzle: 800 blocks = 8 XCDs x 100 contiguous chunks (bijective)
    int bid0 = blockIdx.x;
    int bid = (bid0 & 7)*100 + (bid0 >> 3);
    int t = bid / 400;
    int r = bid - t*400;
    int th0 = (r / 20)*TS, tw0 = (r - (r/20)*20)*TS;
    int tid = threadIdx.y*64 + threadIdx.x;

    for (int i = tid; i < NPOS; i += 256) {
        int rr = reflect(th0 + i/PS - PAD, HH);
        int cc = reflect(tw0 + i%PS - PAD, WW);
        sp[i] = spix[t*HWSZ + rr*WW + cc];
    }
    // stage xpT from xT: coalesced 16B loads, XOR-swizzled 16B-chunk writes
    {
        const _Float16* xt = xT + (size_t)t*HWSZ*64;
        for (int i = tid; i < NPOS*8; i += 256) {
            int pos = i >> 3, cb = i & 7;
            int rr = reflect(th0 + pos/PS - PAD, HH);
            int cc = reflect(tw0 + pos%PS - PAD, WW);
            uint4v v = *(const uint4v*)(xt + (size_t)(rr*WW + cc)*64 + cb*8);
            int chunk = cb ^ (pos & 7);
            *(uint4v*)&xpT[pos*64 + chunk*8] = v;
        }
    }
    __syncthreads();

    int ln = threadIdx.x;
    int wv = __builtin_amdgcn_readfirstlane(threadIdx.y);

    // rw build (raw f16; per-pixel max to mxp; normalization applied in epilogue)
    int p_ = threadIdx.x;
    int ty = threadIdx.y;
    int py0 = p_ >> 3, px0 = p_ & 7;
    {
        float sc = scale[t*HWSZ + (th0 + py0)*WW + (tw0 + px0)];
        int s0 = sp[(py0 + PAD)*PS + (px0 + PAD)];
        const float* pr = pwd + (t*NSPIX + s0)*NSPIX;
        float pmax = 0.f;
        for (int k = ty; k < K2; k += 4) {
            int di = k/KS, dj = k - di*KS;
            int nb = sp[(py0 + di)*PS + (px0 + dj)];
            float v = __expf(-sc * pr[nb]);
            rwb[k*64 + p_] = __builtin_bit_cast(unsigned short, (_Float16)v);
            pmax = fmaxf(pmax, v);
        }
        mxp[ty*64 + p_] = pmax;
    }
    // prologue: stage taps 0 and 1; the __syncthreads drains both (one-time cost)
    stageA(Wb, &Ast[0][0], 0, wv, ln);
    stageA(Wb, &Ast[1][0], 1, wv, ln);
    __syncthreads();

    int qp = wv & 1, kh = wv >> 1;
    int p  = qp*32 + (ln & 31);
    int ppy = p >> 3, ppx = p & 7;
    int lhi = ln >> 5;

    int jc0 = 4*kh + lhi, jc1 = jc0 + 2;
    int aoff = 2*kh*512 + ln*8;   // within-buf f16 offset of A00

    f32x16 acc0, acc1;
    #pragma unroll
    for (int i = 0; i < 16; ++i) { acc0[i] = 0.f; acc1[i] = 0.f; }

    int di = 0, dj = 0;
    for (int tap = 0; tap < K2; ++tap) {
        // compute current tap from Ast[tap&1]
        const _Float16* ab = &Ast[tap & 1][aoff];
        half8 A00 = *(const half8*)(ab);
        half8 A01 = *(const half8*)(ab + 512);
        half8 A10 = *(const half8*)(ab + 2048);
        half8 A11 = *(const half8*)(ab + 2048 + 512);

        int pos = (ppy + di)*PS + (ppx + dj);
        int sw  = pos & 7;
        const unsigned short* bbase = &xpT[pos*64];
        half8 B0 = *(const half8*)(bbase + ((jc0 ^ sw) << 3));
        half8 B1 = *(const half8*)(bbase + ((jc1 ^ sw) << 3));

        _Float16 rh = __builtin_bit_cast(_Float16, rwb[tap*64 + p]);
        half8 rv8 = { rh, rh, rh, rh, rh, rh, rh, rh };
        half8 b0 = B0 * rv8;
        half8 b1 = B1 * rv8;

        __builtin_amdgcn_s_setprio(1);
        acc0 = __builtin_amdgcn_mfma_f32_32x32x16_f16(A00, b0, acc0, 0, 0, 0);
        acc1 = __builtin_amdgcn_mfma_f32_32x32x16_f16(A10, b0, acc1, 0, 0, 0);
        acc0 = __builtin_amdgcn_mfma_f32_32x32x16_f16(A01, b1, acc0, 0, 0, 0);
        acc1 = __builtin_amdgcn_mfma_f32_32x32x16_f16(A11, b1, acc1, 0, 0, 0);
        __builtin_amdgcn_s_setprio(0);

        if (tap < K2 - 1) {
            // own LDS reads (A/B/rwb) complete before others may overwrite Ast
            asm volatile("s_waitcnt lgkmcnt(0)" ::: "memory");
            __builtin_amdgcn_s_barrier();
            if (tap + 2 < K2) {
                stageA(Wb, &Ast[tap & 1][0], tap + 2, wv, ln);
                // wait tap+1's 2 loads (issued one full tap ago); tap+2's stay in flight
                asm volatile("s_waitcnt vmcnt(2)" ::: "memory");
            } else {
                asm volatile("s_waitcnt vmcnt(0)" ::: "memory");
            }
            __builtin_amdgcn_s_barrier();   // all waves' tap+1 staging visible
        }
        if (++dj == KS) { dj = 0; ++di; }
    }

    // cross-kh reduction (reuse xpT as f32 buffer)
    __syncthreads();
    float* red = (float*)xpT;
    if (kh == 1) {
        #pragma unroll
        for (int i = 0; i < 16; ++i) {
            red[((qp*2 + 0)*16 + i)*64 + ln] = acc0[i];
            red[((qp*2 + 1)*16 + i)*64 + ln] = acc1[i];
        }
    }
    __syncthreads();
    if (kh == 0) {
        // per-pixel normalizer, factored out of the einsum
        float m = fmaxf(fmaxf(mxp[p], mxp[64 + p]), fmaxf(mxp[128 + p], mxp[192 + p]));
        float s = 1.f/(1e-5f + m);
        int h = th0 + ppy, w = tw0 + ppx;
        int row_hi = 4*lhi;
        float* ob = out + (size_t)t*OO*HWSZ + h*WW + w;
        #pragma unroll
        for (int rg = 0; rg < 16; ++rg) {
            int o0 = (rg & 3) + 8*(rg >> 2) + row_hi;
            int o1 = 32 + o0;
            float v0 = acc0[rg] + red[((qp*2 + 0)*16 + rg)*64 + ln];
            float v1 = acc1[rg] + red[((qp*2 + 1)*16 + rg)*64 + ln];
            ob[(size_t)o0*HWSZ] = v0*s + b_lin[o0];
            ob[(size_t)o1*HWSZ] = v1*s + b_lin[o1];
        }
    }
}

extern "C" void kernel_launch(void* const* d_in, const int* in_sizes, int n_in,
                              void* d_out, int out_size, void* d_ws, size_t ws_size,
                              hipStream_t stream) {
    const float* x    = (const float*)d_in[0];
    const int*   spix = (const int*)d_in[1];
    const float* Wl   = (const float*)d_in[2];
    const float* bl   = (const float*)d_in[3];
    const float* wsc  = (const float*)d_in[4];
    const float* bsc  = (const float*)d_in[5];
    float* out = (float*)d_out;

    float* ws    = (float*)d_ws;
    float* sums  = ws;                           // 25088 f32
    float* cnts  = sums + TT*NSPIX*CC;           // 392
    float* pwd   = cnts + TT*NSPIX;              // 76832
    float* scale = pwd  + TT*NSPIX*NSPIX;        // 51200
    _Float16* Wb = (_Float16*)(scale + TT*HWSZ); // 200704 f16
    _Float16* xT = Wb + (size_t)2*K2*4*64*8;     // 3276800 f16 (6.55 MB)

    hipMemsetAsync(sums, 0, (size_t)(TT*NSPIX*CC + TT*NSPIX)*sizeof(float), stream);

    k_prep<<<698, 256, 0, stream>>>(x, spix, Wl, wsc, bsc, sums, cnts, scale, Wb, xT);
    k_pwd <<<(TT*NSPIX*NSPIX + 255)/256, 256, 0, stream>>>(sums, cnts, pwd);

    dim3 blk(64, 4, 1);
    k_main<<<TT*400, blk, 0, stream>>>(xT, spix, Wb, bl, pwd, scale, out);
}

// Round 8
// 148.832 us; speedup vs baseline: 3.1339x; 1.1296x over previous
//
#include <hip/hip_runtime.h>
#include <math.h>

#define TT 2
#define CC 64
#define HH 160
#define WW 160
#define KS 7
#define K2 49
#define NSPIX 196
#define HWSZ (HH*WW)
#define PAD 3
#define OO 64
#define FANIN (CC*K2)
#define TS 8
#define PS (TS+KS-1)   // 14
#define NPOS (PS*PS)   // 196

#define NCHUNK 25
#define CHUNKPIX 1024

typedef _Float16 half8 __attribute__((ext_vector_type(8)));
typedef float f32x16 __attribute__((ext_vector_type(16)));
typedef unsigned int uint4v __attribute__((ext_vector_type(4)));
typedef _Float16 half2v __attribute__((ext_vector_type(2)));

__device__ __forceinline__ int reflect(int i, int n) {
    if (i < 0) i = -i;
    if (i >= n) i = 2*n - 2 - i;
    return i;
}

// fused prep: [0,400) seg (4-consecutive-px runs, LDS accumulate + atomic flush);
//             [400,600) scale + xT (f16 transposed) emit; [600,698) Wb (f16) build
__global__ __launch_bounds__(256) void k_prep(const float* __restrict__ x,
                                              const int* __restrict__ spix,
                                              const float* __restrict__ Wl,
                                              const float* __restrict__ wsc,
                                              const float* __restrict__ bsc,
                                              float* __restrict__ sums,
                                              float* __restrict__ cnts,
                                              float* __restrict__ scale,
                                              _Float16* __restrict__ Wb,
                                              _Float16* __restrict__ xT) {
    __shared__ float ls[8*200];
    __shared__ float lcnt[200];
    int bid = blockIdx.x;
    int tid = threadIdx.x;

    if (bid < 400) {
        int cg = bid & 7;
        int rest = bid >> 3;          // 0..49
        int ch = rest % NCHUNK;       // 0..24
        int t  = rest / NCHUNK;       // 0..1

        for (int i = tid; i < 8*200; i += 256) ls[i] = 0.f;
        if (cg == 0) for (int i = tid; i < 200; i += 256) lcnt[i] = 0.f;
        __syncthreads();

        // each thread owns 4 CONSECUTIVE pixels: float4/int4 loads stay coalesced,
        // and spatial coherence of spix makes ~3/4 of quads single-segment ->
        // one LDS atomic per channel carrying the 4-px partial sum.
        int base = ch*CHUNKPIX;
        const int4* sp4 = (const int4*)(spix + t*HWSZ + base);
        int4 sv = sp4[tid];
        bool uni = (sv.x == sv.y) && (sv.y == sv.z) && (sv.z == sv.w);
        if (cg == 0) {
            if (uni) atomicAdd(&lcnt[sv.x], 4.0f);
            else {
                atomicAdd(&lcnt[sv.x], 1.f); atomicAdd(&lcnt[sv.y], 1.f);
                atomicAdd(&lcnt[sv.z], 1.f); atomicAdd(&lcnt[sv.w], 1.f);
            }
        }
        const float* xb = x + ((size_t)t*CC + cg*8)*HWSZ + base;
        #pragma unroll
        for (int j = 0; j < 8; ++j) {
            float4 xv = *(const float4*)(xb + (size_t)j*HWSZ + tid*4);
            float* lj = &ls[j*200];
            if (uni) {
                atomicAdd(&lj[sv.x], xv.x + xv.y + xv.z + xv.w);
            } else {
                if (sv.x == sv.y) atomicAdd(&lj[sv.x], xv.x + xv.y);
                else { atomicAdd(&lj[sv.x], xv.x); atomicAdd(&lj[sv.y], xv.y); }
                if (sv.z == sv.w) atomicAdd(&lj[sv.z], xv.z + xv.w);
                else { atomicAdd(&lj[sv.z], xv.z); atomicAdd(&lj[sv.w], xv.w); }
            }
        }
        __syncthreads();

        float* sb = sums + (size_t)t*NSPIX*CC + cg*8;
        for (int i = tid; i < 8*NSPIX; i += 256) {
            int s = i >> 3, j = i & 7;
            float v = ls[j*200 + s];
            if (v != 0.f) atomicAdd(&sb[s*CC + j], v);
        }
        if (cg == 0)
            for (int i = tid; i < NSPIX; i += 256) {
                float v = lcnt[i];
                if (v != 0.f) atomicAdd(&cnts[t*NSPIX + i], v);
            }
    } else if (bid < 600) {
        int pix = (bid - 400)*256 + tid;
        int t = pix / HWSZ, hw = pix - t*HWSZ;
        const float* xs = x + (size_t)t*CC*HWSZ + hw;
        float s1 = 0.f, s2 = 0.f;
        unsigned int pk[32];
        #pragma unroll
        for (int cp = 0; cp < 32; ++cp) {
            float v0 = xs[(size_t)(2*cp)*HWSZ];
            float v1 = xs[(size_t)(2*cp + 1)*HWSZ];
            s1 += wsc[2*cp]*v0 + wsc[2*cp+1]*v1;
            s2 = fmaf(v0, v0, s2); s2 = fmaf(v1, v1, s2);
            half2v h; h[0] = (_Float16)v0; h[1] = (_Float16)v1;
            pk[cp] = __builtin_bit_cast(unsigned int, h);
        }
        float z = s1/(sqrtf(s2) + 1e-10f) + bsc[0];
        float sp_ = (z > 0.f) ? z + log1pf(expf(-z)) : log1pf(expf(z));
        scale[pix] = 10.f*sp_;
        uint4v* dst = (uint4v*)(xT + (size_t)pix*64);
        #pragma unroll
        for (int q = 0; q < 8; ++q) {
            uint4v v = { pk[4*q], pk[4*q+1], pk[4*q+2], pk[4*q+3] };
            dst[q] = v;
        }
    } else {
        int row = (bid - 600)*256 + tid;
        if (row < 2*K2*4*64) {
            int ln  = row & 63;
            int kc  = (row >> 6) & 3;
            int tq  = row >> 8;
            int tap = tq % K2;
            int qo  = tq / K2;
            int o = qo*32 + (ln & 31);
            int cb = kc*16 + (ln >> 5)*8;
            _Float16* dst = Wb + (size_t)row*8;
            const float* src = Wl + (size_t)o*FANIN + tap;
            #pragma unroll
            for (int j = 0; j < 8; ++j) dst[j] = (_Float16)src[(size_t)(cb + j)*K2];
        }
    }
}

// pwd directly from sums/cnts: pwd[t,s,u] = sum_c (down_s[c]-down_u[c])^2
__global__ __launch_bounds__(256) void k_pwd(const float* __restrict__ sums,
                                             const float* __restrict__ cnts,
                                             float* __restrict__ pwd) {
    int tid = blockIdx.x*256 + threadIdx.x;
    if (tid >= TT*NSPIX*NSPIX) return;
    int t = tid / (NSPIX*NSPIX); int r = tid - t*NSPIX*NSPIX;
    int s = r / NSPIX, u = r - (r / NSPIX)*NSPIX;
    const float4* ds4 = (const float4*)(sums + (size_t)(t*NSPIX + s)*CC);
    const float4* du4 = (const float4*)(sums + (size_t)(t*NSPIX + u)*CC);
    float is = 1.0f / fmaxf(cnts[t*NSPIX + s], 1.0f);
    float iu = 1.0f / fmaxf(cnts[t*NSPIX + u], 1.0f);
    float acc = 0.f;
    #pragma unroll
    for (int q = 0; q < 16; ++q) {
        float4 a = ds4[q], b = du4[q];
        float d0 = a.x*is - b.x*iu;
        float d1 = a.y*is - b.y*iu;
        float d2 = a.z*is - b.z*iu;
        float d3 = a.w*is - b.w*iu;
        acc = fmaf(d0, d0, acc);
        acc = fmaf(d1, d1, acc);
        acc = fmaf(d2, d2, acc);
        acc = fmaf(d3, d3, acc);
    }
    pwd[tid] = acc;
}

// MFMA main — the proven R1 structure (direct global A loads, compiler-scheduled,
// no in-loop barriers) + XCD swizzle (R7: FETCH 14->6 MB) + u16 rwb + epilogue norm.
// R0/R4/R7 established: explicit pipelining/staging regresses this structure.
__global__ __launch_bounds__(256, 4) void k_main(
    const _Float16* __restrict__ xT, const int* __restrict__ spix,
    const _Float16* __restrict__ Wb, const float* __restrict__ b_lin,
    const float* __restrict__ pwd, const float* __restrict__ scale,
    float* __restrict__ out)
{
    __shared__ unsigned short xpT[NPOS*64];   // 25088 B, XOR-swizzled f16
    __shared__ unsigned short rwb[K2*64];     // 6272 B (f16)
    __shared__ int   sp[NPOS];                // 784 B
    __shared__ float mxp[4*64];               // 1024 B
    // total 33168 B -> 4 blocks/CU

    // XCD-aware swizzle: 800 blocks = 8 XCDs x 100 contiguous chunks (bijective)
    int bid0 = blockIdx.x;
    int bid = (bid0 & 7)*100 + (bid0 >> 3);
    int t = bid / 400;
    int r = bid - t*400;
    int th0 = (r / 20)*TS, tw0 = (r - (r/20)*20)*TS;
    int tid = threadIdx.y*64 + threadIdx.x;

    for (int i = tid; i < NPOS; i += 256) {
        int rr = reflect(th0 + i/PS - PAD, HH);
        int cc = reflect(tw0 + i%PS - PAD, WW);
        sp[i] = spix[t*HWSZ + rr*WW + cc];
    }
    // stage xpT from xT: coalesced 16B loads, XOR-swizzled 16B-chunk writes
    {
        const _Float16* xt = xT + (size_t)t*HWSZ*64;
        for (int i = tid; i < NPOS*8; i += 256) {
            int pos = i >> 3, cb = i & 7;
            int rr = reflect(th0 + pos/PS - PAD, HH);
            int cc = reflect(tw0 + pos%PS - PAD, WW);
            uint4v v = *(const uint4v*)(xt + (size_t)(rr*WW + cc)*64 + cb*8);
            int chunk = cb ^ (pos & 7);
            *(uint4v*)&xpT[pos*64 + chunk*8] = v;
        }
    }
    __syncthreads();

    // rw build (raw f16; per-pixel max to mxp; normalization applied in epilogue)
    int p_ = threadIdx.x;
    int ty = threadIdx.y;
    int py0 = p_ >> 3, px0 = p_ & 7;
    {
        float sc = scale[t*HWSZ + (th0 + py0)*WW + (tw0 + px0)];
        int s0 = sp[(py0 + PAD)*PS + (px0 + PAD)];
        const float* pr = pwd + (t*NSPIX + s0)*NSPIX;
        float pmax = 0.f;
        for (int k = ty; k < K2; k += 4) {
            int di = k/KS, dj = k - di*KS;
            int nb = sp[(py0 + di)*PS + (px0 + dj)];
            float v = __expf(-sc * pr[nb]);
            rwb[k*64 + p_] = __builtin_bit_cast(unsigned short, (_Float16)v);
            pmax = fmaxf(pmax, v);
        }
        mxp[ty*64 + p_] = pmax;
    }
    __syncthreads();

    int ln = threadIdx.x;
    int wv = __builtin_amdgcn_readfirstlane(threadIdx.y);
    int qp = wv & 1, kh = wv >> 1;
    int p  = qp*32 + (ln & 31);
    int ppy = p >> 3, ppx = p & 7;
    int lhi = ln >> 5;

    int jc0 = 4*kh + lhi, jc1 = jc0 + 2;

    const _Float16* A0b = Wb + (size_t)(2*kh)*512 + ln*8;   // qo=0, kc0=2kh
    const _Float16* A1b = A0b + (size_t)K2*4*512;           // qo=1

    f32x16 acc0, acc1;
    #pragma unroll
    for (int i = 0; i < 16; ++i) { acc0[i] = 0.f; acc1[i] = 0.f; }

    int di = 0, dj = 0;
    #pragma unroll 7
    for (int tap = 0; tap < K2; ++tap) {
        const _Float16* a0 = A0b + (size_t)tap*2048;
        half8 A00 = *(const half8*)(a0);
        half8 A01 = *(const half8*)(a0 + 512);
        const _Float16* a1 = A1b + (size_t)tap*2048;
        half8 A10 = *(const half8*)(a1);
        half8 A11 = *(const half8*)(a1 + 512);

        int pos = (ppy + di)*PS + (ppx + dj);
        int sw  = pos & 7;
        const unsigned short* bbase = &xpT[pos*64];
        half8 B0 = *(const half8*)(bbase + ((jc0 ^ sw) << 3));
        half8 B1 = *(const half8*)(bbase + ((jc1 ^ sw) << 3));

        _Float16 rh = __builtin_bit_cast(_Float16, rwb[tap*64 + p]);
        half8 rv8 = { rh, rh, rh, rh, rh, rh, rh, rh };
        half8 b0 = B0 * rv8;
        half8 b1 = B1 * rv8;

        acc0 = __builtin_amdgcn_mfma_f32_32x32x16_f16(A00, b0, acc0, 0, 0, 0);
        acc1 = __builtin_amdgcn_mfma_f32_32x32x16_f16(A10, b0, acc1, 0, 0, 0);
        acc0 = __builtin_amdgcn_mfma_f32_32x32x16_f16(A01, b1, acc0, 0, 0, 0);
        acc1 = __builtin_amdgcn_mfma_f32_32x32x16_f16(A11, b1, acc1, 0, 0, 0);

        if (++dj == KS) { dj = 0; ++di; }
    }

    // cross-kh reduction (reuse xpT as f32 buffer)
    __syncthreads();
    float* red = (float*)xpT;
    if (kh == 1) {
        #pragma unroll
        for (int i = 0; i < 16; ++i) {
            red[((qp*2 + 0)*16 + i)*64 + ln] = acc0[i];
            red[((qp*2 + 1)*16 + i)*64 + ln] = acc1[i];
        }
    }
    __syncthreads();
    if (kh == 0) {
        // per-pixel normalizer, factored out of the einsum
        float m = fmaxf(fmaxf(mxp[p], mxp[64 + p]), fmaxf(mxp[128 + p], mxp[192 + p]));
        float s = 1.f/(1e-5f + m);
        int h = th0 + ppy, w = tw0 + ppx;
        int row_hi = 4*lhi;
        float* ob = out + (size_t)t*OO*HWSZ + h*WW + w;
        #pragma unroll
        for (int rg = 0; rg < 16; ++rg) {
            int o0 = (rg & 3) + 8*(rg >> 2) + row_hi;
            int o1 = 32 + o0;
            float v0 = acc0[rg] + red[((qp*2 + 0)*16 + rg)*64 + ln];
            float v1 = acc1[rg] + red[((qp*2 + 1)*16 + rg)*64 + ln];
            ob[(size_t)o0*HWSZ] = v0*s + b_lin[o0];
            ob[(size_t)o1*HWSZ] = v1*s + b_lin[o1];
        }
    }
}

extern "C" void kernel_launch(void* const* d_in, const int* in_sizes, int n_in,
                              void* d_out, int out_size, void* d_ws, size_t ws_size,
                              hipStream_t stream) {
    const float* x    = (const float*)d_in[0];
    const int*   spix = (const int*)d_in[1];
    const float* Wl   = (const float*)d_in[2];
    const float* bl   = (const float*)d_in[3];
    const float* wsc  = (const float*)d_in[4];
    const float* bsc  = (const float*)d_in[5];
    float* out = (float*)d_out;

    float* ws    = (float*)d_ws;
    float* sums  = ws;                           // 25088 f32
    float* cnts  = sums + TT*NSPIX*CC;           // 392
    float* pwd   = cnts + TT*NSPIX;              // 76832
    float* scale = pwd  + TT*NSPIX*NSPIX;        // 51200
    _Float16* Wb = (_Float16*)(scale + TT*HWSZ); // 200704 f16
    _Float16* xT = Wb + (size_t)2*K2*4*64*8;     // 3276800 f16 (6.55 MB)

    hipMemsetAsync(sums, 0, (size_t)(TT*NSPIX*CC + TT*NSPIX)*sizeof(float), stream);

    k_prep<<<698, 256, 0, stream>>>(x, spix, Wl, wsc, bsc, sums, cnts, scale, Wb, xT);
    k_pwd <<<(TT*NSPIX*NSPIX + 255)/256, 256, 0, stream>>>(sums, cnts, pwd);

    dim3 blk(64, 4, 1);
    k_main<<<TT*400, blk, 0, stream>>>(xT, spix, Wb, bl, pwd, scale, out);
}